// Round 3
// baseline (499.920 us; speedup 1.0000x reference)
//
#include <hip/hip_runtime.h>
#include <cstdint>
#include <cstddef>

// Strategy (R3):
//  1) absmax partials (no atomics) with 4-way load ILP; tiny final reduce.
//  2) fused quantize x->int8 [M,K], W->int8 [N,K], 4-way ILP, exact ref ops.
//  3) int8 MFMA GEMM: BK=128 (32KB LDS, halves barrier count vs BK=64),
//     global_load_lds width 16, 8-slot XOR swizzle (slot = chunk ^ (row&7)),
//     XCD-aware tile mapping, LDS-transpose epilogue with full-128B-line
//     float4 stores (kills write-allocate fills seen as FETCH_SIZE=156MB).

typedef int v4i __attribute__((ext_vector_type(4)));

__device__ __forceinline__ void async_copy16(const void* g, void* s) {
  __builtin_amdgcn_global_load_lds(
      (const __attribute__((address_space(1))) void*)g,
      (__attribute__((address_space(3))) void*)s, 16, 0, 0);
}

__device__ __forceinline__ float max4(float4 v) {
  return fmaxf(fmaxf(fabsf(v.x), fabsf(v.y)), fmaxf(fabsf(v.z), fabsf(v.w)));
}

__device__ __forceinline__ float block_max(float m) {
  __shared__ float smax[4];
#pragma unroll
  for (int off = 32; off > 0; off >>= 1)
    m = fmaxf(m, __shfl_down(m, off, 64));
  if ((threadIdx.x & 63) == 0) smax[threadIdx.x >> 6] = m;
  __syncthreads();
  return fmaxf(fmaxf(smax[0], smax[1]), fmaxf(smax[2], smax[3]));
}

#define NBX 2048  // partial blocks for x
#define NBW 1024  // partial blocks for W

__global__ __launch_bounds__(256) void absmax_partial_kernel(
    const float4* __restrict__ x, int xn4, const float4* __restrict__ w,
    int wn4, float* __restrict__ px, float* __restrict__ pw) {
  const float4* src;
  float* dst;
  int n4, bid, nb;
  if (blockIdx.x < NBX) {
    src = x; n4 = xn4; dst = px; bid = blockIdx.x; nb = NBX;
  } else {
    src = w; n4 = wn4; dst = pw; bid = blockIdx.x - NBX; nb = NBW;
  }
  const int s = nb * 256;
  float m = 0.0f;
  int i = bid * 256 + threadIdx.x;
  for (; i + 3 * s < n4; i += 4 * s) {  // 4 independent loads in flight
    float4 a = src[i], b = src[i + s], c = src[i + 2 * s], d = src[i + 3 * s];
    m = fmaxf(m, fmaxf(fmaxf(max4(a), max4(b)), fmaxf(max4(c), max4(d))));
  }
  for (; i < n4; i += s) m = fmaxf(m, max4(src[i]));
  m = block_max(m);
  if (threadIdx.x == 0) dst[bid] = m;
}

__global__ __launch_bounds__(256) void absmax_final_kernel(
    const float* __restrict__ px, const float* __restrict__ pw,
    float* __restrict__ sat) {
  const float* src = (blockIdx.x == 0) ? px : pw;
  const int n = (blockIdx.x == 0) ? NBX : NBW;
  float m = 0.0f;
  for (int i = threadIdx.x; i < n; i += 256) m = fmaxf(m, src[i]);
  m = block_max(m);
  if (threadIdx.x == 0) sat[blockIdx.x] = m;
}

__device__ __forceinline__ int quant4(float4 v, float scale) {
  int a = (int)fminf(fmaxf(rintf(v.x / scale), -128.0f), 127.0f);
  int b = (int)fminf(fmaxf(rintf(v.y / scale), -128.0f), 127.0f);
  int c = (int)fminf(fmaxf(rintf(v.z / scale), -128.0f), 127.0f);
  int d = (int)fminf(fmaxf(rintf(v.w / scale), -128.0f), 127.0f);
  return (a & 255) | ((b & 255) << 8) | ((c & 255) << 16) | ((d & 255) << 24);
}

#define QBX 4096
#define QBW 2048

__global__ __launch_bounds__(256) void quant_fused_kernel(
    const float4* __restrict__ x, int xn4, const float4* __restrict__ w,
    int wn4, const float* __restrict__ sat, int* __restrict__ xq,
    int* __restrict__ wq) {
  const float4* src;
  int* q;
  int n4, bid, nb;
  float scale;
  if (blockIdx.x < QBX) {
    src = x; q = xq; n4 = xn4; bid = blockIdx.x; nb = QBX;
    scale = fmaxf(sat[0], 1e-8f) / 127.0f;
  } else {
    src = w; q = wq; n4 = wn4; bid = blockIdx.x - QBX; nb = QBW;
    scale = fmaxf(sat[1], 1e-8f) / 127.0f;
  }
  const int s = nb * 256;
  int i = bid * 256 + threadIdx.x;
  for (; i + 3 * s < n4; i += 4 * s) {
    float4 a = src[i], b = src[i + s], c = src[i + 2 * s], d = src[i + 3 * s];
    q[i] = quant4(a, scale);
    q[i + s] = quant4(b, scale);
    q[i + 2 * s] = quant4(c, scale);
    q[i + 3 * s] = quant4(d, scale);
  }
  for (; i < n4; i += s) q[i] = quant4(src[i], scale);
}

// C[m,n] = sum_k A[m,k]*B[n,k]  (A = x_int8 [M,K], B = w_int8 [N,K]).
__global__ __launch_bounds__(256) void i8_gemm_kernel(
    const signed char* __restrict__ Aq, const signed char* __restrict__ Bq,
    const float* __restrict__ bias, const float* __restrict__ sat,
    float* __restrict__ out, int M, int N, int K) {
  __shared__ __align__(16) signed char smem[2 * 128 * 128];  // 32 KB
  signed char* Als = smem;
  signed char* Bls = smem + 128 * 128;

  const int tid = threadIdx.x;
  const int lane = tid & 63;
  const int wave = tid >> 6;
  const int wm = (wave & 1) * 64;
  const int wn = (wave >> 1) * 64;

  // XCD-aware mapping: bid&7 -> XCD (dispatch heuristic, perf-only). Each XCD
  // owns an 8-m-tile stripe; within it, sweep n fastest so its A-tile (0.5MB)
  // is L2-resident with 32x reuse; B (16MB) stays L3-resident.
  const int ntn = N >> 7, ntm = M >> 7;
  int bm, bn;
  if ((ntm & 7) == 0) {
    const int g = blockIdx.x & 7;
    const int j = blockIdx.x >> 3;
    bm = g * (ntm >> 3) + j / ntn;
    bn = j % ntn;
  } else {
    bm = blockIdx.x / ntn;
    bn = blockIdx.x % ntn;
  }
  const int M0 = bm * 128;
  const int N0 = bn * 128;

  // Staging: LDS slot forced to base+lane*16 by global_load_lds. Slot (row,sc)
  // holds global chunk cg = sc ^ (row&7). Thread tid -> row=tid>>3, sc=tid&7;
  // passes p add +32 rows ((row+32p)&7 == row&7, same swizzle).
  const int srow = tid >> 3;
  const int sc = tid & 7;
  const int cg = sc ^ (srow & 7);
  const signed char* Ag = Aq + (size_t)(M0 + srow) * K + cg * 16;
  const signed char* Bg = Bq + (size_t)(N0 + srow) * K + cg * 16;
  signed char* AlsP = &Als[tid * 16];  // == Als[srow*128 + sc*16]
  signed char* BlsP = &Bls[tid * 16];

  v4i acc[4][4] = {};

  const int r15 = lane & 15;
  const int qd = lane >> 4;

  for (int kt = 0; kt < K; kt += 128) {
    __syncthreads();
#pragma unroll
    for (int p = 0; p < 4; ++p) {
      async_copy16(Ag + kt + (size_t)(32 * p) * K, AlsP + 4096 * p);
      async_copy16(Bg + kt + (size_t)(32 * p) * K, BlsP + 4096 * p);
    }
    __syncthreads();

#pragma unroll
    for (int h = 0; h < 2; ++h) {
      v4i af[4], bf[4];
      const int slot = ((qd + 4 * h) ^ (r15 & 7)) * 16;  // de-swizzled chunk
#pragma unroll
      for (int t = 0; t < 4; ++t) {
        af[t] = *(const v4i*)&Als[(wm + t * 16 + r15) * 128 + slot];
        bf[t] = *(const v4i*)&Bls[(wn + t * 16 + r15) * 128 + slot];
      }
#pragma unroll
      for (int tm = 0; tm < 4; ++tm)
#pragma unroll
        for (int tn = 0; tn < 4; ++tn)
          acc[tm][tn] = __builtin_amdgcn_mfma_i32_16x16x64_i8(
              af[tm], bf[tn], acc[tm][tn], 0, 0, 0);
    }
  }

  const float act_s = fmaxf(sat[0], 1e-8f) / 127.0f;
  const float w_s = fmaxf(sat[1], 1e-8f) / 127.0f;
  const float bscale = act_s * w_s;

  float fb[4];
#pragma unroll
  for (int tn = 0; tn < 4; ++tn)
    fb[tn] = rintf(bias[N0 + wn + tn * 16 + r15] / bscale);

  // LDS-transpose epilogue: per tm, wave writes its biased+scaled 16x64 fp32
  // sub-tile to a private LDS region (stride 68 floats: 2-way banks = free),
  // reads back row-fragments as float4 and stores 8 rows x 128B full lines.
  __syncthreads();  // all waves done ds_reading A/B tiles before overwrite
  float* T = (float*)smem + wave * (16 * 68);
#pragma unroll
  for (int tm = 0; tm < 4; ++tm) {
#pragma unroll
    for (int tn = 0; tn < 4; ++tn)
#pragma unroll
      for (int r = 0; r < 4; ++r)
        T[(qd * 4 + r) * 68 + tn * 16 + r15] =
            ((float)acc[tm][tn][r] + fb[tn]) * bscale;
    // same-wave DS ops are pipeline-ordered; compiler inserts lgkmcnt waits
#pragma unroll
    for (int p = 0; p < 4; ++p) {
      const int lr = (p & 1) * 8 + (lane >> 3);   // local row 0..15
      const int f4 = (p >> 1) * 8 + (lane & 7);   // float4 index 0..15
      float4 v = *(const float4*)&T[lr * 68 + f4 * 4];
      *(float4*)&out[(size_t)(M0 + wm + tm * 16 + lr) * N + N0 + wn + f4 * 4] =
          v;
    }
  }
}

extern "C" void kernel_launch(void* const* d_in, const int* in_sizes, int n_in,
                              void* d_out, int out_size, void* d_ws,
                              size_t ws_size, hipStream_t stream) {
  const float* x = (const float*)d_in[0];
  const float* W = (const float*)d_in[1];
  const float* b = (const float*)d_in[2];
  float* out = (float*)d_out;

  const int Dout = in_sizes[2];      // 4096
  const int K = in_sizes[1] / Dout;  // 4096
  const int M = in_sizes[0] / K;     // 8192
  const int N = Dout;

  // ws layout: sat[2] | px[NBX] | pw[NBW] | (16KB align) xq[M*K] | wq[N*K]
  float* sat = (float*)d_ws;
  float* px = sat + 16;
  float* pw = px + NBX;
  signed char* xq = (signed char*)d_ws + 16384;
  signed char* wq = xq + (size_t)M * K;

  const int xn4 = in_sizes[0] / 4;
  const int wn4 = in_sizes[1] / 4;

  absmax_partial_kernel<<<NBX + NBW, 256, 0, stream>>>(
      (const float4*)x, xn4, (const float4*)W, wn4, px, pw);
  absmax_final_kernel<<<2, 256, 0, stream>>>(px, pw, sat);
  quant_fused_kernel<<<QBX + QBW, 256, 0, stream>>>(
      (const float4*)x, xn4, (const float4*)W, wn4, sat, (int*)xq, (int*)wq);

  i8_gemm_kernel<<<(M / 128) * (N / 128), 256, 0, stream>>>(xq, wq, b, sat,
                                                            out, M, N, K);
}